// Round 1
// baseline (54.157 us; speedup 1.0000x reference)
//
#include <hip/hip_runtime.h>
#include <math.h>

// Problem constants (from reference): B=16, NODE=25, FRAME=128, N=3200.
#define BATCH 16
#define NTOT  3200
#define BLOCK 256
#define SUBS  4                      // threads cooperating per output row
#define ROWS_PER_BLOCK (BLOCK / SUBS)        // 64
#define BLOCKS_PER_B   (NTOT / ROWS_PER_BLOCK) // 50

__device__ inline float fast_exp2(float v) {
#if __has_builtin(__builtin_amdgcn_exp2f)
    return __builtin_amdgcn_exp2f(v);
#else
    return exp2f(v);
#endif
}

__global__ __launch_bounds__(BLOCK) void rank1_attn_kernel(
    const float* __restrict__ x,                     // [B, N]
    const float* __restrict__ w1p, const float* __restrict__ b1p,
    const float* __restrict__ w2p, const float* __restrict__ b2p,
    float* __restrict__ out)                         // [B, N]
{
    // Interleaved {d_n, x_n} so the inner loop is one ds_read_b64.
    __shared__ float2 dx[NTOT];
    __shared__ float red[8];                         // per-wave max/min partials

    const int bid     = blockIdx.x;
    const int b       = bid / BLOCKS_PER_B;
    const int rowBase = (bid % BLOCKS_PER_B) * ROWS_PER_BLOCK;
    const int t       = threadIdx.x;

    const float w1 = *w1p, b1 = *b1p, w2 = *w2p, b2 = *b2p;
    const float* xb = x + b * NTOT;

    // Stage x and d = w2*x + b2 into LDS; track global min/max of d for this b.
    float dmx = -INFINITY, dmn = INFINITY;
    for (int n = t; n < NTOT; n += BLOCK) {
        float xv = xb[n];
        float dv = fmaf(w2, xv, b2);
        dx[n] = make_float2(dv, xv);
        dmx = fmaxf(dmx, dv);
        dmn = fminf(dmn, dv);
    }
    // 64-lane butterfly reduce, then cross-wave via LDS.
    #pragma unroll
    for (int off = 1; off < 64; off <<= 1) {
        dmx = fmaxf(dmx, __shfl_xor(dmx, off));
        dmn = fminf(dmn, __shfl_xor(dmn, off));
    }
    const int wid = t >> 6;
    if ((t & 63) == 0) { red[wid] = dmx; red[4 + wid] = dmn; }
    __syncthreads();
    dmx = fmaxf(fmaxf(red[0], red[1]), fmaxf(red[2], red[3]));
    dmn = fminf(fminf(red[4], red[5]), fminf(red[6], red[7]));

    const int m   = rowBase + (t >> 2);              // output row this thread helps
    const int sub = t & (SUBS - 1);

    const float xm = dx[m].y;
    const float a  = fmaf(w1, xm, b1);
    const float LOG2E = 1.44269504088896340736f;
    const float am2 = a * LOG2E;
    // Analytic row max: max_n a*d_n = a*dmax (a>=0) or a*dmin (a<0), in log2 units.
    const float M2  = am2 * (a >= 0.0f ? dmx : dmn);

    float sum = 0.0f, wsum = 0.0f;
    for (int n = sub; n < NTOT; n += SUBS) {
        float2 v = dx[n];
        float e  = fast_exp2(fmaf(am2, v.x, -M2));
        sum  += e;
        wsum  = fmaf(v.y, e, wsum);
    }
    // Reduce across the 4 cooperating lanes (consecutive lane ids).
    sum += __shfl_xor(sum, 1);  wsum += __shfl_xor(wsum, 1);
    sum += __shfl_xor(sum, 2);  wsum += __shfl_xor(wsum, 2);

    if (sub == 0) out[b * NTOT + m] = wsum / sum + xm;
}

extern "C" void kernel_launch(void* const* d_in, const int* in_sizes, int n_in,
                              void* d_out, int out_size, void* d_ws, size_t ws_size,
                              hipStream_t stream) {
    const float* x  = (const float*)d_in[0];
    const float* w1 = (const float*)d_in[1];
    const float* b1 = (const float*)d_in[2];
    const float* w2 = (const float*)d_in[3];
    const float* b2 = (const float*)d_in[4];
    float* out = (float*)d_out;

    dim3 grid(BATCH * BLOCKS_PER_B);   // 800 blocks
    dim3 block(BLOCK);
    rank1_attn_kernel<<<grid, block, 0, stream>>>(x, w1, b1, w2, b2, out);
}

// Round 2
// 30.719 us; speedup vs baseline: 1.7630x; 1.7630x over previous
//
#include <hip/hip_runtime.h>
#include <math.h>

// Problem constants (from reference): B=16, NODE=25, FRAME=128, N=3200.
#define BATCH 16
#define NTOT  3200
#define BLOCK 256
#define SUBS  8                               // threads cooperating per output row
#define ROWS_PER_BLOCK (BLOCK / SUBS)         // 32
#define BLOCKS_PER_B   (NTOT / ROWS_PER_BLOCK) // 100 -> grid 1600 (6.25/CU)
#define ITERS (NTOT / (SUBS * 4))             // 100 float4 iterations per thread

__device__ inline float fast_exp2(float v) {
#if __has_builtin(__builtin_amdgcn_exp2f)
    return __builtin_amdgcn_exp2f(v);
#else
    return exp2f(v);
#endif
}

__global__ __launch_bounds__(BLOCK) void rank1_attn_kernel(
    const float* __restrict__ x,                     // [B, N]
    const float* __restrict__ w1p, const float* __restrict__ b1p,
    const float* __restrict__ w2p, const float* __restrict__ b2p,
    float* __restrict__ out)                         // [B, N]
{
    __shared__ float xs[NTOT];                       // 12.8 KB
    __shared__ float red[8];                         // per-wave max/min partials

    const int bid     = blockIdx.x;
    const int b       = bid / BLOCKS_PER_B;
    const int rowBase = (bid % BLOCKS_PER_B) * ROWS_PER_BLOCK;
    const int t       = threadIdx.x;

    const float w1 = *w1p, b1 = *b1p, w2 = *w2p, b2 = *b2p;
    (void)b2;  // cancels inside softmax
    const float* xb = x + b * NTOT;

    // Stage x into LDS (float4), tracking min/max of x for this batch.
    float mx = -INFINITY, mn = INFINITY;
    const float4* xb4 = (const float4*)xb;
    float4* xs4 = (float4*)xs;
    for (int i = t; i < NTOT / 4; i += BLOCK) {      // 3-4 iters/thread
        float4 v = xb4[i];
        xs4[i] = v;
        mx = fmaxf(fmaxf(mx, v.x), fmaxf(v.y, fmaxf(v.z, v.w)));
        mn = fminf(fminf(mn, v.x), fminf(v.y, fminf(v.z, v.w)));
    }
    #pragma unroll
    for (int off = 1; off < 64; off <<= 1) {
        mx = fmaxf(mx, __shfl_xor(mx, off));
        mn = fminf(mn, __shfl_xor(mn, off));
    }
    const int wid = t >> 6;
    if ((t & 63) == 0) { red[wid] = mx; red[4 + wid] = mn; }
    __syncthreads();
    const float xmax = fmaxf(fmaxf(red[0], red[1]), fmaxf(red[2], red[3]));
    const float xmin = fminf(fminf(red[4], red[5]), fminf(red[6], red[7]));

    const int m   = rowBase + (t >> 3);              // output row this thread helps
    const int sub = t & (SUBS - 1);

    const float xm = xs[m];
    const float LOG2E = 1.44269504088896340736f;
    // softmax weights ∝ exp2(t2 * x_n); a*b2 term cancels.
    const float t2 = fmaf(w1, xm, b1) * w2 * LOG2E;
    const float M2 = t2 * (t2 >= 0.0f ? xmax : xmin); // analytic row max (log2 units)

    // sub s reads float4 #(k*8 + s): 8 distinct 16B segments span 128B = all 32 banks.
    const float4* p = (const float4*)xs;
    float sumA = 0.0f, sumB = 0.0f, wsA = 0.0f, wsB = 0.0f;
    #pragma unroll 4
    for (int k = 0; k < ITERS; ++k) {
        float4 v = p[k * SUBS + sub];
        float e0 = fast_exp2(fmaf(t2, v.x, -M2));
        float e1 = fast_exp2(fmaf(t2, v.y, -M2));
        float e2 = fast_exp2(fmaf(t2, v.z, -M2));
        float e3 = fast_exp2(fmaf(t2, v.w, -M2));
        sumA += e0 + e1;      sumB += e2 + e3;
        wsA   = fmaf(v.x, e0, wsA);  wsA = fmaf(v.y, e1, wsA);
        wsB   = fmaf(v.z, e2, wsB);  wsB = fmaf(v.w, e3, wsB);
    }
    float sum = sumA + sumB, ws = wsA + wsB;
    // Reduce across the 8 cooperating lanes (consecutive lane ids).
    #pragma unroll
    for (int off = 1; off < SUBS; off <<= 1) {
        sum += __shfl_xor(sum, off);
        ws  += __shfl_xor(ws,  off);
    }

    if (sub == 0) out[b * NTOT + m] = ws / sum + xm;
}

extern "C" void kernel_launch(void* const* d_in, const int* in_sizes, int n_in,
                              void* d_out, int out_size, void* d_ws, size_t ws_size,
                              hipStream_t stream) {
    const float* x  = (const float*)d_in[0];
    const float* w1 = (const float*)d_in[1];
    const float* b1 = (const float*)d_in[2];
    const float* w2 = (const float*)d_in[3];
    const float* b2 = (const float*)d_in[4];
    float* out = (float*)d_out;

    dim3 grid(BATCH * BLOCKS_PER_B);   // 1600 blocks
    dim3 block(BLOCK);
    rank1_attn_kernel<<<grid, block, 0, stream>>>(x, w1, b1, w2, b2, out);
}

// Round 3
// 13.219 us; speedup vs baseline: 4.0969x; 2.3238x over previous
//
#include <hip/hip_runtime.h>
#include <math.h>

// B=16, NODE=25, FRAME=128 -> N=3200 per batch.
// out[b,m] = F_b(t_m) + x[b,m],  t_m = (w1*w2)*x_m + b1*w2,
// F_b(t) = sum_n x_n e^{t x_n} / sum_n e^{t x_n}   (b2 cancels in softmax).
// F_b is smooth & monotone in t -> tabulate K points over realized t-range, lerp.

#define BATCH 16
#define NTOT  3200
#define N4    (NTOT / 4)          // 800 float4s
#define K     512
#define KBLOCKS 64                // phase-1 blocks per batch
#define KPB   (K / KBLOCKS)       // 8 t-points per block
#define SUBW  32                  // lanes per t-point
#define BLOCK 256
#define LOG2E 1.44269504088896340736f

__device__ inline float fast_exp2(float v) {
#if __has_builtin(__builtin_amdgcn_exp2f)
    return __builtin_amdgcn_exp2f(v);
#else
    return exp2f(v);
#endif
}

__global__ __launch_bounds__(BLOCK) void table_kernel(
    const float* __restrict__ x,
    const float* __restrict__ w1p, const float* __restrict__ b1p,
    const float* __restrict__ w2p,
    float* __restrict__ table, float2* __restrict__ params)
{
    __shared__ float4 xs4[N4];    // 12.8 KB
    __shared__ float red[8];

    const int bid = blockIdx.x;
    const int b   = bid >> 6;                 // / KBLOCKS
    const int kb  = bid & (KBLOCKS - 1);
    const int t   = threadIdx.x;

    const float w1 = *w1p, b1 = *b1p, w2 = *w2p;
    const float c1 = w1 * w2, c0 = b1 * w2;

    // Stage x (float4) + batch min/max.
    const float4* xb4 = (const float4*)(x + b * NTOT);
    float mx = -INFINITY, mn = INFINITY;
    for (int i = t; i < N4; i += BLOCK) {
        float4 v = xb4[i];
        xs4[i] = v;
        mx = fmaxf(fmaxf(mx, v.x), fmaxf(v.y, fmaxf(v.z, v.w)));
        mn = fminf(fminf(mn, v.x), fminf(v.y, fminf(v.z, v.w)));
    }
    #pragma unroll
    for (int off = 1; off < 64; off <<= 1) {
        mx = fmaxf(mx, __shfl_xor(mx, off));
        mn = fminf(mn, __shfl_xor(mn, off));
    }
    const int wid = t >> 6;
    if ((t & 63) == 0) { red[wid] = mx; red[4 + wid] = mn; }
    __syncthreads();
    const float xmax = fmaxf(fmaxf(red[0], red[1]), fmaxf(red[2], red[3]));
    const float xmin = fminf(fminf(red[4], red[5]), fminf(red[6], red[7]));

    // Realized t-range over this batch's rows.
    const float tmin  = (c1 >= 0.f) ? fmaf(c1, xmin, c0) : fmaf(c1, xmax, c0);
    const float tmax  = (c1 >= 0.f) ? fmaf(c1, xmax, c0) : fmaf(c1, xmin, c0);
    const float delta = (tmax - tmin) * (1.0f / (K - 1));

    const int g = t >> 5;                     // 0..7: which t-point
    const int s = t & (SUBW - 1);
    const int k = kb * KPB + g;
    const float tk = fmaf((float)k, delta, tmin);
    const float a2 = tk * LOG2E;
    const float M2 = a2 * ((a2 >= 0.f) ? xmax : xmin);   // analytic row max (log2)

    float sA = 0.f, sB = 0.f, wA = 0.f, wB = 0.f;
    #pragma unroll 5
    for (int i = 0; i < N4 / SUBW; ++i) {     // 25 iters, 4 exps each
        float4 v = xs4[s + SUBW * i];
        float e0 = fast_exp2(fmaf(a2, v.x, -M2));
        float e1 = fast_exp2(fmaf(a2, v.y, -M2));
        float e2 = fast_exp2(fmaf(a2, v.z, -M2));
        float e3 = fast_exp2(fmaf(a2, v.w, -M2));
        sA += e0 + e1;  sB += e2 + e3;
        wA = fmaf(v.x, e0, wA);  wA = fmaf(v.y, e1, wA);
        wB = fmaf(v.z, e2, wB);  wB = fmaf(v.w, e3, wB);
    }
    float sum = sA + sB, ws = wA + wB;
    #pragma unroll
    for (int off = 1; off < SUBW; off <<= 1) {
        sum += __shfl_xor(sum, off);
        ws  += __shfl_xor(ws,  off);
    }
    if (s == 0) table[b * K + k] = ws / sum;              // F_b(t_k)
    if (kb == 0 && t == 0)
        params[b] = make_float2(tmin, delta != 0.f ? 1.0f / delta : 0.f);
}

__global__ __launch_bounds__(BLOCK) void apply_kernel(
    const float* __restrict__ x,
    const float* __restrict__ w1p, const float* __restrict__ b1p,
    const float* __restrict__ w2p,
    const float* __restrict__ table, const float2* __restrict__ params,
    float* __restrict__ out)
{
    const int gid = blockIdx.x * BLOCK + threadIdx.x;     // 51200 exact
    const int b   = gid / NTOT;
    const float xm = x[gid];
    const float c1 = (*w1p) * (*w2p), c0 = (*b1p) * (*w2p);
    const float2 pr = params[b];

    float u = (fmaf(c1, xm, c0) - pr.x) * pr.y;           // grid coordinate
    u = fminf(fmaxf(u, 0.f), (float)(K - 1));
    int i = (int)u;
    i = min(i, K - 2);
    const float frac = u - (float)i;
    const float* tb = table + b * K;
    const float lo = tb[i], hi = tb[i + 1];
    out[gid] = fmaf(frac, hi - lo, lo) + xm;
}

extern "C" void kernel_launch(void* const* d_in, const int* in_sizes, int n_in,
                              void* d_out, int out_size, void* d_ws, size_t ws_size,
                              hipStream_t stream) {
    const float* x  = (const float*)d_in[0];
    const float* w1 = (const float*)d_in[1];
    const float* b1 = (const float*)d_in[2];
    const float* w2 = (const float*)d_in[3];
    const float* b2 = (const float*)d_in[4];
    (void)b2;  // cancels inside softmax
    float* out = (float*)d_out;

    float*  table  = (float*)d_ws;
    float2* params = (float2*)((char*)d_ws + BATCH * K * sizeof(float));

    table_kernel<<<BATCH * KBLOCKS, BLOCK, 0, stream>>>(x, w1, b1, w2, table, params);
    apply_kernel<<<(BATCH * NTOT) / BLOCK, BLOCK, 0, stream>>>(x, w1, b1, w2, table, params, out);
}

// Round 4
// 11.799 us; speedup vs baseline: 4.5899x; 1.1203x over previous
//
#include <hip/hip_runtime.h>
#include <math.h>

// B=16, NODE=25, FRAME=128 -> N=3200 per batch.
// out[b,m] = F_b(t_m) + x[b,m],  t_m = (w1*w2)*x_m + b1*w2,
// F_b(t) = sum_n x_n e^{t x_n} / sum_n e^{t x_n}   (b2 cancels in softmax).
// F_b smooth & monotone -> tabulate K points over realized t-range, lerp.

#define BATCH 16
#define NTOT  3200
#define N4    (NTOT / 4)          // 800 float4s per batch
#define K     256
#define KBLOCKS 32                // phase-1 blocks per batch  (grid 512 = 2/CU)
#define KPB   (K / KBLOCKS)       // 8 t-points per block
#define SUBW  32                  // lanes per t-point
#define BLOCK 256
#define LOG2E 1.44269504088896340736f

__device__ inline float fast_exp2(float v) {
#if __has_builtin(__builtin_amdgcn_exp2f)
    return __builtin_amdgcn_exp2f(v);
#else
    return exp2f(v);
#endif
}

__global__ __launch_bounds__(BLOCK) void table_kernel(
    const float* __restrict__ x,
    const float* __restrict__ w1p, const float* __restrict__ b1p,
    const float* __restrict__ w2p,
    float* __restrict__ table, float2* __restrict__ params)
{
    __shared__ float4 xs4[N4];    // 12.8 KB
    __shared__ float red[8];

    const int bid = blockIdx.x;
    const int b   = bid >> 5;                 // / KBLOCKS
    const int kb  = bid & (KBLOCKS - 1);
    const int t   = threadIdx.x;

    const float w1 = *w1p, b1 = *b1p, w2 = *w2p;
    const float c1 = w1 * w2, c0 = b1 * w2;

    // Stage x (float4) + batch min/max.
    const float4* xb4 = (const float4*)(x + b * NTOT);
    float mx = -INFINITY, mn = INFINITY;
    for (int i = t; i < N4; i += BLOCK) {
        float4 v = xb4[i];
        xs4[i] = v;
        mx = fmaxf(fmaxf(mx, v.x), fmaxf(v.y, fmaxf(v.z, v.w)));
        mn = fminf(fminf(mn, v.x), fminf(v.y, fminf(v.z, v.w)));
    }
    #pragma unroll
    for (int off = 1; off < 64; off <<= 1) {
        mx = fmaxf(mx, __shfl_xor(mx, off));
        mn = fminf(mn, __shfl_xor(mn, off));
    }
    const int wid = t >> 6;
    if ((t & 63) == 0) { red[wid] = mx; red[4 + wid] = mn; }
    __syncthreads();
    const float xmax = fmaxf(fmaxf(red[0], red[1]), fmaxf(red[2], red[3]));
    const float xmin = fminf(fminf(red[4], red[5]), fminf(red[6], red[7]));

    // Realized t-range over this batch's rows.
    const float tmin  = (c1 >= 0.f) ? fmaf(c1, xmin, c0) : fmaf(c1, xmax, c0);
    const float tmax  = (c1 >= 0.f) ? fmaf(c1, xmax, c0) : fmaf(c1, xmin, c0);
    const float delta = (tmax - tmin) * (1.0f / (K - 1));

    const int g = t >> 5;                     // 0..7: which t-point of this block
    const int s = t & (SUBW - 1);
    const int k = kb * KPB + g;
    const float tk = fmaf((float)k, delta, tmin);
    const float a2 = tk * LOG2E;
    const float M2 = a2 * ((a2 >= 0.f) ? xmax : xmin);   // analytic max (log2)

    float sA = 0.f, sB = 0.f, wA = 0.f, wB = 0.f;
    #pragma unroll 5
    for (int i = 0; i < N4 / SUBW; ++i) {     // 25 iters, 4 exps each
        float4 v = xs4[s + SUBW * i];
        float e0 = fast_exp2(fmaf(a2, v.x, -M2));
        float e1 = fast_exp2(fmaf(a2, v.y, -M2));
        float e2 = fast_exp2(fmaf(a2, v.z, -M2));
        float e3 = fast_exp2(fmaf(a2, v.w, -M2));
        sA += e0 + e1;  sB += e2 + e3;
        wA = fmaf(v.x, e0, wA);  wA = fmaf(v.y, e1, wA);
        wB = fmaf(v.z, e2, wB);  wB = fmaf(v.w, e3, wB);
    }
    float sum = sA + sB, ws = wA + wB;
    #pragma unroll
    for (int off = 1; off < SUBW; off <<= 1) {
        sum += __shfl_xor(sum, off);
        ws  += __shfl_xor(ws,  off);
    }
    if (s == 0) table[b * K + k] = ws / sum;              // F_b(t_k)
    if (kb == 0 && t == 0)
        params[b] = make_float2(tmin, delta != 0.f ? 1.0f / delta : 0.f);
}

__global__ __launch_bounds__(BLOCK) void apply_kernel(
    const float* __restrict__ x,
    const float* __restrict__ w1p, const float* __restrict__ b1p,
    const float* __restrict__ w2p,
    const float* __restrict__ table, const float2* __restrict__ params,
    float* __restrict__ out)
{
    const int gid4 = blockIdx.x * BLOCK + threadIdx.x;    // 12800 exact
    const int b    = gid4 / (N4);                          // 800 float4/batch
    const float c1 = (*w1p) * (*w2p), c0 = (*b1p) * (*w2p);
    const float2 pr = params[b];
    const float* tb = table + b * K;

    float4 xv = ((const float4*)x)[gid4];
    float4 ov;
    #pragma unroll
    for (int j = 0; j < 4; ++j) {
        float xm = (&xv.x)[j];
        float u = (fmaf(c1, xm, c0) - pr.x) * pr.y;        // grid coordinate
        u = fminf(fmaxf(u, 0.f), (float)(K - 1));
        int i = min((int)u, K - 2);
        float frac = u - (float)i;
        float lo = tb[i], hi = tb[i + 1];
        (&ov.x)[j] = fmaf(frac, hi - lo, lo) + xm;
    }
    ((float4*)out)[gid4] = ov;
}

extern "C" void kernel_launch(void* const* d_in, const int* in_sizes, int n_in,
                              void* d_out, int out_size, void* d_ws, size_t ws_size,
                              hipStream_t stream) {
    const float* x  = (const float*)d_in[0];
    const float* w1 = (const float*)d_in[1];
    const float* b1 = (const float*)d_in[2];
    const float* w2 = (const float*)d_in[3];
    const float* b2 = (const float*)d_in[4];
    (void)b2;  // cancels inside softmax
    float* out = (float*)d_out;

    float*  table  = (float*)d_ws;
    float2* params = (float2*)((char*)d_ws + BATCH * K * sizeof(float));

    table_kernel<<<BATCH * KBLOCKS, BLOCK, 0, stream>>>(x, w1, b1, w2, table, params);
    apply_kernel<<<(BATCH * NTOT) / (BLOCK * 4), BLOCK, 0, stream>>>(
        x, w1, b1, w2, table, params, out);
}